// Round 3
// baseline (3532.027 us; speedup 1.0000x reference)
//
#include <hip/hip_runtime.h>
#include <hip/hip_bf16.h>

#define FEAT 128

// ---- CSR build -------------------------------------------------------------

__global__ void hist_kernel(const int* __restrict__ dst, int* __restrict__ counts, int E) {
    int e = blockIdx.x * 256 + threadIdx.x;
    if (e < E) atomicAdd(&counts[dst[e]], 1);
}

__global__ __launch_bounds__(1024)
void scan_kernel(const int* __restrict__ counts, int* __restrict__ indptr,
                 int* __restrict__ cursor, float* __restrict__ dinv, int n, int E) {
    __shared__ int swave[16];
    __shared__ int s_carry;
    int tid = threadIdx.x, lane = tid & 63, wid = tid >> 6;
    if (tid == 0) s_carry = 0;
    __syncthreads();
    for (int base = 0; base < n; base += 4096) {
        int i4 = base + tid * 4;
        int4 v = {0, 0, 0, 0};
        if (i4 < n) v = *(const int4*)&counts[i4];
        int t = v.x + v.y + v.z + v.w;
        int x = t;
        #pragma unroll
        for (int off = 1; off < 64; off <<= 1) {
            int y = __shfl_up(x, off);
            if (lane >= off) x += y;
        }
        if (lane == 63) swave[wid] = x;
        __syncthreads();
        if (wid == 0 && lane < 16) {
            int s = swave[lane];
            #pragma unroll
            for (int off = 1; off < 16; off <<= 1) {
                int y = __shfl_up(s, off);
                if (lane >= off) s += y;
            }
            swave[lane] = s;
        }
        __syncthreads();
        int waveoff = (wid > 0) ? swave[wid - 1] : 0;
        int carry = s_carry;
        if (i4 < n) {
            int e0 = carry + waveoff + x - t;
            int p[4];
            p[0] = e0;
            p[1] = e0 + v.x;
            p[2] = p[1] + v.y;
            p[3] = p[2] + v.z;
            int c[4] = {v.x, v.y, v.z, v.w};
            #pragma unroll
            for (int j = 0; j < 4; ++j) {
                indptr[i4 + j] = p[j];
                cursor[i4 + j] = p[j];
                dinv[i4 + j]   = rsqrtf((float)(c[j] + 1));
            }
        }
        __syncthreads();
        if (tid == 1023) s_carry = carry + swave[15];
        __syncthreads();
    }
    if (threadIdx.x == 0) indptr[n] = E;
}

__global__ void fill_kernel(const int* __restrict__ src, const int* __restrict__ dst,
                            int* __restrict__ cursor, int* __restrict__ ssrc, int E) {
    int e = blockIdx.x * 256 + threadIdx.x;
    if (e < E) {
        int d = dst[e];
        int pos = atomicAdd(&cursor[d], 1);
        ssrc[pos] = src[e];
    }
}

// ---- GEMM (fp32 VALU, LDS-tiled): hs[row] = (in[row] @ W) * dinv[row] -------
// Block: 256 threads, tile = 64 rows x 64 cols (blockIdx.y = col half).
// LDS: W-half 128x64 (32 KB) + x-tile 64x132-padded (33 KB) -> 2 blocks/CU.
// Per thread: 4 rows x 4 cols register tile, K consumed in float4 groups.

__global__ __launch_bounds__(256)
void gemm_f32(const float* __restrict__ in, const float* __restrict__ W,
              const float* __restrict__ dinv, float* __restrict__ hs, int n) {
    __shared__ float ws[128][64];
    __shared__ float xs[64][132];

    const int tid = threadIdx.x;
    const int rowbase = blockIdx.x * 64;
    const int coly = blockIdx.y;            // 0 or 1

    const float4* Wv = (const float4*)W;    // W[k][c] as float4 over c (32 per k)
    const float4* Xv = (const float4*)in;

    // stage W half: 128 k x 16 float4
    #pragma unroll
    for (int s = 0; s < 8; ++s) {
        int idx = s * 256 + tid;            // 0..2047
        int k = idx >> 4, c4 = idx & 15;
        float4 wv = Wv[k * 32 + coly * 16 + c4];
        *(float4*)&ws[k][c4 * 4] = wv;
    }
    // stage x tile: 64 rows x 32 float4
    #pragma unroll
    for (int s = 0; s < 8; ++s) {
        int idx = s * 256 + tid;
        int r = idx >> 5, c4 = idx & 31;
        int row = rowbase + r;
        if (row >= n) row = n - 1;
        float4 xv = Xv[(size_t)row * 32 + c4];
        *(float4*)&xs[r][c4 * 4] = xv;
    }
    __syncthreads();

    const int tx = tid & 15;                // col group (4 cols)
    const int ty = tid >> 4;                // row group (4 rows)

    float4 acc[4];
    #pragma unroll
    for (int r = 0; r < 4; ++r) acc[r] = make_float4(0.f, 0.f, 0.f, 0.f);

    #pragma unroll
    for (int k0 = 0; k0 < 128; k0 += 4) {
        float4 wk[4], xr[4];
        #pragma unroll
        for (int i = 0; i < 4; ++i) wk[i] = *(const float4*)&ws[k0 + i][tx * 4];
        #pragma unroll
        for (int r = 0; r < 4; ++r) xr[r] = *(const float4*)&xs[ty * 4 + r][k0];
        #pragma unroll
        for (int r = 0; r < 4; ++r) {
            acc[r].x += xr[r].x * wk[0].x; acc[r].y += xr[r].x * wk[0].y;
            acc[r].z += xr[r].x * wk[0].z; acc[r].w += xr[r].x * wk[0].w;
            acc[r].x += xr[r].y * wk[1].x; acc[r].y += xr[r].y * wk[1].y;
            acc[r].z += xr[r].y * wk[1].z; acc[r].w += xr[r].y * wk[1].w;
            acc[r].x += xr[r].z * wk[2].x; acc[r].y += xr[r].z * wk[2].y;
            acc[r].z += xr[r].z * wk[2].z; acc[r].w += xr[r].z * wk[2].w;
            acc[r].x += xr[r].w * wk[3].x; acc[r].y += xr[r].w * wk[3].y;
            acc[r].z += xr[r].w * wk[3].z; acc[r].w += xr[r].w * wk[3].w;
        }
    }

    const int colf4 = coly * 16 + tx;       // float4 index within the 32-wide row
    #pragma unroll
    for (int r = 0; r < 4; ++r) {
        int row = rowbase + ty * 4 + r;
        if (row < n) {
            float d = dinv[row];
            float4 o = acc[r];
            o.x *= d; o.y *= d; o.z *= d; o.w *= d;
            ((float4*)(hs + (size_t)row * FEAT))[colf4] = o;
        }
    }
}

// ---- aggregation: out[i] = act( dinv[i] * (hs[i] + sum_{e: dst=i} hs[src_e]) + b )

__global__ __launch_bounds__(256)
void agg_kernel(const float* __restrict__ hs, const int* __restrict__ indptr,
                const int* __restrict__ ssrc, const float* __restrict__ dinv,
                const float* __restrict__ bias, float* __restrict__ out,
                int n, int do_relu) {
    int wid = threadIdx.x >> 6, lane = threadIdx.x & 63;
    int node = blockIdx.x * 4 + wid;
    if (node >= n) return;

    const float2* hs2 = (const float2*)hs;
    float2 a0 = hs2[(size_t)node * 64 + lane];   // self-loop (pre-scaled by dinv[node])
    float2 a1 = {0.f, 0.f};

    int start = indptr[node], end = indptr[node + 1];
    for (int e0 = start; e0 < end; e0 += 64) {
        int cnt = end - e0;
        if (cnt > 64) cnt = 64;
        int sv = (lane < cnt) ? ssrc[e0 + lane] : 0;
        int j = 0;
        for (; j + 4 <= cnt; j += 4) {
            int s0 = __shfl(sv, j);
            int s1 = __shfl(sv, j + 1);
            int s2 = __shfl(sv, j + 2);
            int s3 = __shfl(sv, j + 3);
            float2 v0 = hs2[(size_t)s0 * 64 + lane];
            float2 v1 = hs2[(size_t)s1 * 64 + lane];
            float2 v2 = hs2[(size_t)s2 * 64 + lane];
            float2 v3 = hs2[(size_t)s3 * 64 + lane];
            a0.x += v0.x; a0.y += v0.y;
            a1.x += v1.x; a1.y += v1.y;
            a0.x += v2.x; a0.y += v2.y;
            a1.x += v3.x; a1.y += v3.y;
        }
        for (; j < cnt; ++j) {
            int s = __shfl(sv, j);
            float2 v = hs2[(size_t)s * 64 + lane];
            a0.x += v.x; a0.y += v.y;
        }
    }

    float d = dinv[node];
    float2 bv = ((const float2*)bias)[lane];
    float ox = (a0.x + a1.x) * d + bv.x;
    float oy = (a0.y + a1.y) * d + bv.y;
    if (do_relu) { ox = fmaxf(ox, 0.f); oy = fmaxf(oy, 0.f); }
    float2 o; o.x = ox; o.y = oy;
    ((float2*)out)[(size_t)node * 64 + lane] = o;
}

// ---- launch ----------------------------------------------------------------

static inline size_t align256(size_t x) { return (x + 255) & ~(size_t)255; }

extern "C" void kernel_launch(void* const* d_in, const int* in_sizes, int n_in,
                              void* d_out, int out_size, void* d_ws, size_t ws_size,
                              hipStream_t stream) {
    const float* x  = (const float*)d_in[0];
    const int*   ei = (const int*)d_in[1];
    const float* W1 = (const float*)d_in[2];
    const float* b1 = (const float*)d_in[3];
    const float* W2 = (const float*)d_in[4];
    const float* b2 = (const float*)d_in[5];
    const float* W3 = (const float*)d_in[6];
    const float* b3 = (const float*)d_in[7];

    int n = in_sizes[0] / FEAT;      // 100000
    int E = in_sizes[1] / 2;         // 1600000
    const int* src = ei;
    const int* dst = ei + E;

    // workspace carve-up (~59 MB)
    char* w = (char*)d_ws;
    int* counts  = (int*)w;                   w += align256((size_t)n * 4);
    int* indptr  = (int*)w;                   w += align256((size_t)(n + 1) * 4);
    int* cursor  = (int*)w;                   w += align256((size_t)n * 4);
    float* dinv  = (float*)w;                 w += align256((size_t)n * 4);
    int* ssrc    = (int*)w;                   w += align256((size_t)E * 4);
    float* hs    = (float*)w;                 w += align256((size_t)n * FEAT * 4);

    float* hbuf = (float*)d_out;             // inter-layer activations live in d_out

    hipMemsetAsync(counts, 0, (size_t)n * 4, stream);

    hist_kernel<<<(E + 255) / 256, 256, 0, stream>>>(dst, counts, E);
    scan_kernel<<<1, 1024, 0, stream>>>(counts, indptr, cursor, dinv, n, E);
    fill_kernel<<<(E + 255) / 256, 256, 0, stream>>>(src, dst, cursor, ssrc, E);

    for (int L = 0; L < 3; ++L) {
        const float* gin = (L == 0) ? x : hbuf;
        const float* WL  = (L == 0) ? W1 : (L == 1) ? W2 : W3;
        const float* bb  = (L == 0) ? b1 : (L == 1) ? b2 : b3;

        dim3 ggrid((n + 63) / 64, 2);
        gemm_f32<<<ggrid, 256, 0, stream>>>(gin, WL, dinv, hs, n);
        agg_kernel<<<(n + 3) / 4, 256, 0, stream>>>(hs, indptr, ssrc, dinv, bb, hbuf, n, (L < 2) ? 1 : 0);
    }
}

// Round 4
// 821.396 us; speedup vs baseline: 4.3000x; 4.3000x over previous
//
#include <hip/hip_runtime.h>
#include <hip/hip_bf16.h>

#define FEAT 128

// ---- CSR build -------------------------------------------------------------

__global__ void hist_kernel(const int* __restrict__ dst, int* __restrict__ counts, int E) {
    int e = blockIdx.x * 256 + threadIdx.x;
    if (e < E) atomicAdd(&counts[dst[e]], 1);
}

__global__ __launch_bounds__(1024)
void scan_kernel(const int* __restrict__ counts, int* __restrict__ indptr,
                 int* __restrict__ cursor, float* __restrict__ dinv, int n, int E) {
    __shared__ int swave[16];
    __shared__ int s_carry;
    int tid = threadIdx.x, lane = tid & 63, wid = tid >> 6;
    if (tid == 0) s_carry = 0;
    __syncthreads();
    for (int base = 0; base < n; base += 4096) {
        int i4 = base + tid * 4;
        int4 v = {0, 0, 0, 0};
        if (i4 < n) v = *(const int4*)&counts[i4];
        int t = v.x + v.y + v.z + v.w;
        int x = t;
        #pragma unroll
        for (int off = 1; off < 64; off <<= 1) {
            int y = __shfl_up(x, off);
            if (lane >= off) x += y;
        }
        if (lane == 63) swave[wid] = x;
        __syncthreads();
        if (wid == 0 && lane < 16) {
            int s = swave[lane];
            #pragma unroll
            for (int off = 1; off < 16; off <<= 1) {
                int y = __shfl_up(s, off);
                if (lane >= off) s += y;
            }
            swave[lane] = s;
        }
        __syncthreads();
        int waveoff = (wid > 0) ? swave[wid - 1] : 0;
        int carry = s_carry;
        if (i4 < n) {
            int e0 = carry + waveoff + x - t;
            int p[4];
            p[0] = e0;
            p[1] = e0 + v.x;
            p[2] = p[1] + v.y;
            p[3] = p[2] + v.z;
            int c[4] = {v.x, v.y, v.z, v.w};
            #pragma unroll
            for (int j = 0; j < 4; ++j) {
                indptr[i4 + j] = p[j];
                cursor[i4 + j] = p[j];
                dinv[i4 + j]   = rsqrtf((float)(c[j] + 1));
            }
        }
        __syncthreads();
        if (tid == 1023) s_carry = carry + swave[15];
        __syncthreads();
    }
    if (threadIdx.x == 0) indptr[n] = E;
}

__global__ void fill_kernel(const int* __restrict__ src, const int* __restrict__ dst,
                            int* __restrict__ cursor, int* __restrict__ ssrc, int E) {
    int e = blockIdx.x * 256 + threadIdx.x;
    if (e < E) {
        int d = dst[e];
        int pos = atomicAdd(&cursor[d], 1);
        ssrc[pos] = src[e];
    }
}

// ---- GEMM (fp32 VALU, LDS-tiled): hs[row] = (in[row] @ W) * dinv[row] -------
// Block: 256 threads, tile = 64 rows x 64 cols (blockIdx.y = col half).
// LDS: W-half 128x64 (32 KB) + x-tile 64x132-padded (33 KB) -> 2 blocks/CU.
// Per thread: 4 rows x 4 cols register tile.
// NOTE: outer k-loop is `#pragma unroll 1` — full unroll blew the 256-VGPR cap
// in round 3 (1.5 GB scratch-spill traffic per dispatch, 5x regression).

__global__ __launch_bounds__(256)
void gemm_f32(const float* __restrict__ in, const float* __restrict__ W,
              const float* __restrict__ dinv, float* __restrict__ hs, int n) {
    __shared__ float ws[128][64];
    __shared__ float xs[64][132];

    const int tid = threadIdx.x;
    const int rowbase = blockIdx.x * 64;
    const int coly = blockIdx.y;            // 0 or 1

    const float4* Wv = (const float4*)W;    // W[k][c] as float4 over c (32 per k)
    const float4* Xv = (const float4*)in;

    // stage W half: 128 k x 16 float4
    #pragma unroll
    for (int s = 0; s < 8; ++s) {
        int idx = s * 256 + tid;            // 0..2047
        int k = idx >> 4, c4 = idx & 15;
        float4 wv = Wv[k * 32 + coly * 16 + c4];
        *(float4*)&ws[k][c4 * 4] = wv;
    }
    // stage x tile: 64 rows x 32 float4
    #pragma unroll
    for (int s = 0; s < 8; ++s) {
        int idx = s * 256 + tid;
        int r = idx >> 5, c4 = idx & 31;
        int row = rowbase + r;
        if (row >= n) row = n - 1;
        float4 xv = Xv[(size_t)row * 32 + c4];
        *(float4*)&xs[r][c4 * 4] = xv;
    }
    __syncthreads();

    const int tx = tid & 15;                // col group (4 cols)
    const int ty = tid >> 4;                // row group (4 rows)

    float4 acc[4];
    #pragma unroll
    for (int r = 0; r < 4; ++r) acc[r] = make_float4(0.f, 0.f, 0.f, 0.f);

    #pragma unroll 1
    for (int k0 = 0; k0 < 128; k0 += 8) {
        float4 xr[4][2];
        #pragma unroll
        for (int r = 0; r < 4; ++r) {
            xr[r][0] = *(const float4*)&xs[ty * 4 + r][k0];
            xr[r][1] = *(const float4*)&xs[ty * 4 + r][k0 + 4];
        }
        #pragma unroll
        for (int half = 0; half < 2; ++half) {
            #pragma unroll
            for (int kk = 0; kk < 4; ++kk) {
                float4 wv = *(const float4*)&ws[k0 + half * 4 + kk][tx * 4];
                #pragma unroll
                for (int r = 0; r < 4; ++r) {
                    float xk = (kk == 0) ? xr[r][half].x :
                               (kk == 1) ? xr[r][half].y :
                               (kk == 2) ? xr[r][half].z : xr[r][half].w;
                    acc[r].x += xk * wv.x;
                    acc[r].y += xk * wv.y;
                    acc[r].z += xk * wv.z;
                    acc[r].w += xk * wv.w;
                }
            }
        }
    }

    const int colf4 = coly * 16 + tx;       // float4 index within the 32-wide row
    #pragma unroll
    for (int r = 0; r < 4; ++r) {
        int row = rowbase + ty * 4 + r;
        if (row < n) {
            float d = dinv[row];
            float4 o = acc[r];
            o.x *= d; o.y *= d; o.z *= d; o.w *= d;
            ((float4*)(hs + (size_t)row * FEAT))[colf4] = o;
        }
    }
}

// ---- aggregation: out[i] = act( dinv[i] * (hs[i] + sum_{e: dst=i} hs[src_e]) + b )

__global__ __launch_bounds__(256)
void agg_kernel(const float* __restrict__ hs, const int* __restrict__ indptr,
                const int* __restrict__ ssrc, const float* __restrict__ dinv,
                const float* __restrict__ bias, float* __restrict__ out,
                int n, int do_relu) {
    int wid = threadIdx.x >> 6, lane = threadIdx.x & 63;
    int node = blockIdx.x * 4 + wid;
    if (node >= n) return;

    const float2* hs2 = (const float2*)hs;
    float2 a0 = hs2[(size_t)node * 64 + lane];   // self-loop (pre-scaled by dinv[node])
    float2 a1 = {0.f, 0.f};

    int start = indptr[node], end = indptr[node + 1];
    for (int e0 = start; e0 < end; e0 += 64) {
        int cnt = end - e0;
        if (cnt > 64) cnt = 64;
        int sv = (lane < cnt) ? ssrc[e0 + lane] : 0;
        int j = 0;
        for (; j + 4 <= cnt; j += 4) {
            int s0 = __shfl(sv, j);
            int s1 = __shfl(sv, j + 1);
            int s2 = __shfl(sv, j + 2);
            int s3 = __shfl(sv, j + 3);
            float2 v0 = hs2[(size_t)s0 * 64 + lane];
            float2 v1 = hs2[(size_t)s1 * 64 + lane];
            float2 v2 = hs2[(size_t)s2 * 64 + lane];
            float2 v3 = hs2[(size_t)s3 * 64 + lane];
            a0.x += v0.x; a0.y += v0.y;
            a1.x += v1.x; a1.y += v1.y;
            a0.x += v2.x; a0.y += v2.y;
            a1.x += v3.x; a1.y += v3.y;
        }
        for (; j < cnt; ++j) {
            int s = __shfl(sv, j);
            float2 v = hs2[(size_t)s * 64 + lane];
            a0.x += v.x; a0.y += v.y;
        }
    }

    float d = dinv[node];
    float2 bv = ((const float2*)bias)[lane];
    float ox = (a0.x + a1.x) * d + bv.x;
    float oy = (a0.y + a1.y) * d + bv.y;
    if (do_relu) { ox = fmaxf(ox, 0.f); oy = fmaxf(oy, 0.f); }
    float2 o; o.x = ox; o.y = oy;
    ((float2*)out)[(size_t)node * 64 + lane] = o;
}

// ---- launch ----------------------------------------------------------------

static inline size_t align256(size_t x) { return (x + 255) & ~(size_t)255; }

extern "C" void kernel_launch(void* const* d_in, const int* in_sizes, int n_in,
                              void* d_out, int out_size, void* d_ws, size_t ws_size,
                              hipStream_t stream) {
    const float* x  = (const float*)d_in[0];
    const int*   ei = (const int*)d_in[1];
    const float* W1 = (const float*)d_in[2];
    const float* b1 = (const float*)d_in[3];
    const float* W2 = (const float*)d_in[4];
    const float* b2 = (const float*)d_in[5];
    const float* W3 = (const float*)d_in[6];
    const float* b3 = (const float*)d_in[7];

    int n = in_sizes[0] / FEAT;      // 100000
    int E = in_sizes[1] / 2;         // 1600000
    const int* src = ei;
    const int* dst = ei + E;

    // workspace carve-up (~59 MB)
    char* w = (char*)d_ws;
    int* counts  = (int*)w;                   w += align256((size_t)n * 4);
    int* indptr  = (int*)w;                   w += align256((size_t)(n + 1) * 4);
    int* cursor  = (int*)w;                   w += align256((size_t)n * 4);
    float* dinv  = (float*)w;                 w += align256((size_t)n * 4);
    int* ssrc    = (int*)w;                   w += align256((size_t)E * 4);
    float* hs    = (float*)w;                 w += align256((size_t)n * FEAT * 4);

    float* hbuf = (float*)d_out;             // inter-layer activations live in d_out

    hipMemsetAsync(counts, 0, (size_t)n * 4, stream);

    hist_kernel<<<(E + 255) / 256, 256, 0, stream>>>(dst, counts, E);
    scan_kernel<<<1, 1024, 0, stream>>>(counts, indptr, cursor, dinv, n, E);
    fill_kernel<<<(E + 255) / 256, 256, 0, stream>>>(src, dst, cursor, ssrc, E);

    for (int L = 0; L < 3; ++L) {
        const float* gin = (L == 0) ? x : hbuf;
        const float* WL  = (L == 0) ? W1 : (L == 1) ? W2 : W3;
        const float* bb  = (L == 0) ? b1 : (L == 1) ? b2 : b3;

        dim3 ggrid((n + 63) / 64, 2);
        gemm_f32<<<ggrid, 256, 0, stream>>>(gin, WL, dinv, hs, n);
        agg_kernel<<<(n + 3) / 4, 256, 0, stream>>>(hs, indptr, ssrc, dinv, bb, hbuf, n, (L < 2) ? 1 : 0);
    }
}